// Round 9
// baseline (142.175 us; speedup 1.0000x reference)
//
#include <hip/hip_runtime.h>
#include <math.h>

#define JB   16384
#define FEPS 1e-9f
#define PADX 72     // LDS row stride (ushorts): 144 B, 16B-aligned, <=2-way banks

// ws float offsets — every region fully written before read; NO memset, NO atomics
#define WS_UMP   128      // 512*64 : u_mean partials [i*64+chunk][d]
#define WS_TP0   32896    // 64*8*64 : t0 partials [rc][j][d]
#define WS_TP1   65664    // 64*8*64 : t1 partials
#define WS_R2V   98432    // 16384*8 : r2[rv][j]  (rv = s*32+b, output row order)
#define WS_X7BV  229504   // 524288 fl (1M ushorts): bf16 x7, rv-order [rv][d]
#define WS_BT    753792   // 16384 fl (32K ushorts): Bt[n][k], n = j*64+e

typedef short short8 __attribute__((ext_vector_type(8)));
typedef float f32x4  __attribute__((ext_vector_type(4)));

static __device__ inline ushort f2bf(float f) {
  union { float f; unsigned u; } a; a.f = f;
  unsigned u = a.u;
  u += 0x7fffu + ((u >> 16) & 1u);   // RNE
  return (ushort)(u >> 16);
}
static __device__ inline float bf2f(ushort h) {
  union { unsigned u; float f; } c; c.u = ((unsigned)h) << 16;
  return c.f;
}

// ---------------------------------------------------------------- k_main
// blocks 0..511  : um-scan of x (i = blk>>6, chunk = blk&63, 256 rows);
//                  i==7 blocks also emit bf16 x7 in rv-order.
// blocks 512..1023: MFMA GEMM (rc = bid>>3, j = bid&7) on fp32 x7 ->
//                  r2[rv][j] + t0 partials (c0 = 1/8); rc==0 blocks store bt.
__global__ __launch_bounds__(256) void k_main(const float* __restrict__ x,
                                              const float* __restrict__ w,
                                              float* __restrict__ ws) {
  int blk = blockIdx.x, t = threadIdx.x;
  __shared__ float4 s4[256];          // scan path (4 KB)
  __shared__ float wl[4096];          // gemm path: w7j stage (16 KB)
  __shared__ ushort x7l[128 * PADX];  // gemm path: bf16 rows (18 KB)
  __shared__ float gs[128];
  __shared__ float red[256];
  ushort* x7bv = (ushort*)(ws + WS_X7BV);
  ushort* bt   = (ushort*)(ws + WS_BT);

  if (blk < 512) {                    // ---------- um-scan path
    int i = blk >> 6, c = blk & 63;
    int q = t & 15, rsub = t >> 4;
    const float4* xr = (const float4*)(x + ((size_t)i * JB + c * 256) * 64);
    float4 a = make_float4(0.f, 0.f, 0.f, 0.f);
    for (int rr = rsub; rr < 256; rr += 16) {
      float4 v = xr[rr * 16 + q];
      a.x += v.x; a.y += v.y; a.z += v.z; a.w += v.w;
      if (i == 7) {                   // uniform branch
        ushort4 h = make_ushort4(f2bf(v.x), f2bf(v.y), f2bf(v.z), f2bf(v.w));
        int rn = c * 256 + rr;
        int rv = ((rn & 511) << 5) | (rn >> 9);   // rv = s*32 + b
        *(ushort4*)(x7bv + (size_t)rv * 64 + q * 4) = h;
      }
    }
    s4[t] = a;
    __syncthreads();
    if (t < 16) {
      float4 s = s4[t];
      for (int k = 1; k < 16; ++k) {
        float4 v = s4[t + k * 16];
        s.x += v.x; s.y += v.y; s.z += v.z; s.w += v.w;
      }
      *(float4*)(ws + WS_UMP + (size_t)blk * 64 + t * 4) = s;
    }
    return;
  }

  // ---------- GEMM path
  int bid = blk - 512;
  int j = bid & 7, rc = bid >> 3, rm0 = rc * 256;
  int lane = t & 63, wv = t >> 6, m = lane & 15, quad = lane >> 4;

  const float* w7j = w + (size_t)(56 + j) * 4096;
  #pragma unroll
  for (int k = 0; k < 16; ++k) wl[t + k * 256] = w7j[t + k * 256];
  __syncthreads();

  short8 bfr[4][2];
  #pragma unroll
  for (int nt = 0; nt < 4; ++nt)
    #pragma unroll
    for (int kb = 0; kb < 2; ++kb) {
      short8 hv;
      #pragma unroll
      for (int u = 0; u < 8; ++u)
        hv[u] = (short)f2bf(wl[(kb * 32 + quad * 8 + u) * 64 + nt * 16 + m]);
      bfr[nt][kb] = hv;
    }
  if (rc == 0) {                      // persist bt for k_out
    #pragma unroll
    for (int nt = 0; nt < 4; ++nt)
      #pragma unroll
      for (int kb = 0; kb < 2; ++kb)
        *(short8*)(bt + ((size_t)j * 64 + nt * 16 + m) * 64 + kb * 32 + quad * 8) = bfr[nt][kb];
  }

  const float* x7 = x + (size_t)7 * JB * 64;
  float tacc = 0.f;
  #pragma unroll
  for (int h = 0; h < 2; ++h) {
    #pragma unroll
    for (int s = 0; s < 2; ++s) {
      int rb = rm0 + h * 128 + s * 64 + wv * 16;
      const float* ap = x7 + (size_t)(rb + m) * 64;
      float4 f0 = *(const float4*)(ap + quad * 8);
      float4 f1 = *(const float4*)(ap + quad * 8 + 4);
      float4 f2 = *(const float4*)(ap + 32 + quad * 8);
      float4 f3 = *(const float4*)(ap + 32 + quad * 8 + 4);
      short8 a0, a1;
      a0[0] = (short)f2bf(f0.x); a0[1] = (short)f2bf(f0.y);
      a0[2] = (short)f2bf(f0.z); a0[3] = (short)f2bf(f0.w);
      a0[4] = (short)f2bf(f1.x); a0[5] = (short)f2bf(f1.y);
      a0[6] = (short)f2bf(f1.z); a0[7] = (short)f2bf(f1.w);
      a1[0] = (short)f2bf(f2.x); a1[1] = (short)f2bf(f2.y);
      a1[2] = (short)f2bf(f2.z); a1[3] = (short)f2bf(f2.w);
      a1[4] = (short)f2bf(f3.x); a1[5] = (short)f2bf(f3.y);
      a1[6] = (short)f2bf(f3.z); a1[7] = (short)f2bf(f3.w);
      int lrow = s * 64 + wv * 16 + m;
      *(short8*)(x7l + lrow * PADX + quad * 8) = a0;        // stage for t0
      *(short8*)(x7l + lrow * PADX + 32 + quad * 8) = a1;

      f32x4 acc[4];
      #pragma unroll
      for (int nt = 0; nt < 4; ++nt) acc[nt] = (f32x4){0.f, 0.f, 0.f, 0.f};
      #pragma unroll
      for (int nt = 0; nt < 4; ++nt) {
        acc[nt] = __builtin_amdgcn_mfma_f32_16x16x32_bf16(a0, bfr[nt][0], acc[nt], 0, 0, 0);
        acc[nt] = __builtin_amdgcn_mfma_f32_16x16x32_bf16(a1, bfr[nt][1], acc[nt], 0, 0, 0);
      }
      float sq[4];
      #pragma unroll
      for (int r = 0; r < 4; ++r)
        sq[r] = acc[0][r] * acc[0][r] + acc[1][r] * acc[1][r] +
                acc[2][r] * acc[2][r] + acc[3][r] * acc[3][r];
      #pragma unroll
      for (int mk = 1; mk < 16; mk <<= 1) {
        #pragma unroll
        for (int r = 0; r < 4; ++r) sq[r] += __shfl_xor(sq[r], mk, 64);
      }
      if (m == 0) {
        #pragma unroll
        for (int r = 0; r < 4; ++r) {
          int rn = rb + quad * 4 + r;
          int rv = ((rn & 511) << 5) | (rn >> 9);
          ws[WS_R2V + (size_t)rv * 8 + j] = sq[r];          // rv-order store
          float s2 = 0.015625f * sq[r];                     // (1/8)^2 * r2
          gs[s * 64 + wv * 16 + quad * 4 + r] =
              0.125f * s2 / ((1.f + s2) * sqrtf(s2 + FEPS));
        }
      }
    }
    __syncthreads();
    {
      int d = lane;
      float a = 0.f;
      #pragma unroll 8
      for (int r = 0; r < 32; ++r) {
        int row = wv * 32 + r;
        a += gs[row] * bf2f(x7l[row * PADX + d]);
      }
      tacc += a;
    }
    __syncthreads();
  }
  red[t] = tacc;
  __syncthreads();
  if (t < 64)
    ws[WS_TP0 + (size_t)(rc * 8 + j) * 64 + t] =
        red[t] + red[t + 64] + red[t + 128] + red[t + 192];
}

// ---------------------------------------------------------------- k_t1
// Each block computes c1[j] = softmax(Bd0)[7][j] inline from TP0+UMP
// (bit-identical across blocks: same reduction order), then t1 partials.
// Bd0[i][j] = (1/JB^2) um[i] . ( W[i][j] . ( W7[j]^T t0[j] ) )
__global__ __launch_bounds__(256) void k_t1(const float* __restrict__ w,
                                            float* __restrict__ ws) {
  int t = threadIdx.x, blk = blockIdx.x;
  int lane = t & 63, wv = t >> 6;
  int j = blk & 7, rc = blk >> 3, rm0 = rc * 256;
  __shared__ ushort x7l[128 * PADX];
  __shared__ float gs[128];
  __shared__ float red[256];
  __shared__ float tl0[64], vm0[64], umx[512], pp[512];
  __shared__ float cl;
  ushort* x7bv = (ushort*)(ws + WS_X7BV);

  // ---- phase A: c1[j]
  if (t < 64) {
    float s = 0.f;
    #pragma unroll 8
    for (int c = 0; c < 64; ++c) s += ws[WS_TP0 + (size_t)(c * 8 + j) * 64 + t];
    tl0[t] = s;
  }
  #pragma unroll
  for (int u = 0; u < 2; ++u) {
    int idx = t + u * 256;            // 0..511 = i*64+d
    int i = idx >> 6, d = idx & 63;
    float s = 0.f;
    #pragma unroll 8
    for (int c = 0; c < 64; ++c) s += ws[WS_UMP + (size_t)(i * 64 + c) * 64 + d];
    umx[idx] = s;
  }
  __syncthreads();
  if (t < 64) {
    const float* w7j = w + (size_t)(56 + j) * 4096;
    float acc = 0.f;
    for (int d = 0; d < 64; ++d) acc += w7j[d * 64 + t] * tl0[d];
    vm0[t] = acc * (1.0f / (float)JB);
  }
  __syncthreads();
  #pragma unroll
  for (int u = 0; u < 2; ++u) {
    int idx = t + u * 256;
    int i = idx >> 6, d = idx & 63;
    const float* wij = w + (size_t)(i * 8 + j) * 4096 + d * 64;
    float acc = 0.f;
    for (int e = 0; e < 64; ++e) acc += wij[e] * vm0[e];
    pp[idx] = umx[idx] * acc;
  }
  __syncthreads();
  if (t < 8) {
    float s = 0.f;
    for (int d = 0; d < 64; ++d) s += pp[t * 64 + d];
    red[t] = s * (1.0f / (float)JB);  // Bd0[t][j]
  }
  __syncthreads();
  if (t == 0) {
    float mx = -1e30f;
    for (int i = 0; i < 8; ++i) mx = fmaxf(mx, red[i]);
    float ss = 0.f;
    for (int i = 0; i < 8; ++i) ss += expf(red[i] - mx);
    cl = expf(red[7] - mx) / ss;
  }
  __syncthreads();
  float c1 = cl;

  // ---- phase B: t1 partials
  float tacc = 0.f;
  #pragma unroll
  for (int h = 0; h < 2; ++h) {
    int rbh = rm0 + h * 128;
    #pragma unroll
    for (int k = 0; k < 4; ++k) {
      int c16 = t + k * 256;
      int row = c16 >> 3, seg = c16 & 7;
      *(short8*)(x7l + row * PADX + seg * 8) =
          *(const short8*)(x7bv + (size_t)(rbh + row) * 64 + seg * 8);
    }
    if (t < 128) {
      float r2v = ws[WS_R2V + (size_t)(rbh + t) * 8 + j];
      float s2 = c1 * c1 * r2v;
      gs[t] = c1 * s2 / ((1.f + s2) * sqrtf(s2 + FEPS));
    }
    __syncthreads();
    {
      int d = lane;
      float a = 0.f;
      #pragma unroll 8
      for (int r = 0; r < 32; ++r) {
        int row = wv * 32 + r;
        a += gs[row] * bf2f(x7l[row * PADX + d]);
      }
      tacc += a;
    }
    __syncthreads();
  }
  red[t] = tacc;
  __syncthreads();
  if (t < 64)
    ws[WS_TP1 + (size_t)(rc * 8 + j) * 64 + t] =
        red[t] + red[t + 64] + red[t + 128] + red[t + 192];
}

// ---------------------------------------------------------------- k_out
// Each block computes cf[j] = softmax(Bd0+Bd1)[7][j] inline from TP0+TP1+UMP,
// then out[j][rv][e] = g(cf, r2) * p  (rv-order rows/stores, MFMA GEMM)
__global__ __launch_bounds__(256) void k_out(const float* __restrict__ w,
                                             float* __restrict__ out,
                                             float* __restrict__ ws) {
  int t = threadIdx.x, blk = blockIdx.x;
  int lane = t & 63, wv = t >> 6, m = lane & 15, quad = lane >> 4;
  int j = blk & 7, rc = blk >> 3, rm0 = rc * 256;
  __shared__ float tl0[64], tl1[64], vm0[64], vm1[64], umx[512];
  __shared__ float pp0[512], pp1[512], bd[8];
  __shared__ float cl;
  ushort* x7bv = (ushort*)(ws + WS_X7BV);
  ushort* bt   = (ushort*)(ws + WS_BT);

  // ---- phase A: cf[j]
  if (t < 64) {
    float s = 0.f;
    #pragma unroll 8
    for (int c = 0; c < 64; ++c) s += ws[WS_TP0 + (size_t)(c * 8 + j) * 64 + t];
    tl0[t] = s;
  } else if (t < 128) {
    int d = t - 64;
    float s = 0.f;
    #pragma unroll 8
    for (int c = 0; c < 64; ++c) s += ws[WS_TP1 + (size_t)(c * 8 + j) * 64 + d];
    tl1[d] = s;
  }
  #pragma unroll
  for (int u = 0; u < 2; ++u) {
    int idx = t + u * 256;
    int i = idx >> 6, d = idx & 63;
    float s = 0.f;
    #pragma unroll 8
    for (int c = 0; c < 64; ++c) s += ws[WS_UMP + (size_t)(i * 64 + c) * 64 + d];
    umx[idx] = s;
  }
  __syncthreads();
  if (t < 64) {
    const float* w7j = w + (size_t)(56 + j) * 4096;
    float a0 = 0.f, a1 = 0.f;
    for (int d = 0; d < 64; ++d) {
      float wv2 = w7j[d * 64 + t];
      a0 += wv2 * tl0[d];
      a1 += wv2 * tl1[d];
    }
    vm0[t] = a0 * (1.0f / (float)JB);
    vm1[t] = a1 * (1.0f / (float)JB);
  }
  __syncthreads();
  #pragma unroll
  for (int u = 0; u < 2; ++u) {
    int idx = t + u * 256;
    int i = idx >> 6, d = idx & 63;
    const float* wij = w + (size_t)(i * 8 + j) * 4096 + d * 64;
    float a0 = 0.f, a1 = 0.f;
    for (int e = 0; e < 64; ++e) {
      float wv2 = wij[e];
      a0 += wv2 * vm0[e];
      a1 += wv2 * vm1[e];
    }
    pp0[idx] = umx[idx] * a0;
    pp1[idx] = umx[idx] * a1;
  }
  __syncthreads();
  if (t < 8) {
    float s0 = 0.f, s1 = 0.f;
    for (int d = 0; d < 64; ++d) { s0 += pp0[t * 64 + d]; s1 += pp1[t * 64 + d]; }
    bd[t] = (s0 + s1) * (1.0f / (float)JB);   // Bd0+Bd1 at [t][j]
  }
  __syncthreads();
  if (t == 0) {
    float mx = -1e30f;
    for (int i = 0; i < 8; ++i) mx = fmaxf(mx, bd[i]);
    float ss = 0.f;
    for (int i = 0; i < 8; ++i) ss += expf(bd[i] - mx);
    cl = expf(bd[7] - mx) / ss;
  }
  __syncthreads();
  float cf = cl;

  // ---- phase B: final MFMA GEMM, rv-order
  short8 bfr[4][2];
  const ushort* btj = bt + (size_t)(j * 64) * 64;
  #pragma unroll
  for (int nt = 0; nt < 4; ++nt)
    #pragma unroll
    for (int kb = 0; kb < 2; ++kb)
      bfr[nt][kb] = *(const short8*)(btj + (size_t)(nt * 16 + m) * 64 + kb * 32 + quad * 8);

  #pragma unroll
  for (int h = 0; h < 2; ++h) {
    #pragma unroll
    for (int s = 0; s < 2; ++s) {
      int rb = rm0 + h * 128 + s * 64 + wv * 16;   // rv-order rows
      const ushort* ap = x7bv + (size_t)(rb + m) * 64 + quad * 8;
      short8 a0 = *(const short8*)ap;
      short8 a1 = *(const short8*)(ap + 32);
      f32x4 acc[4];
      #pragma unroll
      for (int nt = 0; nt < 4; ++nt) acc[nt] = (f32x4){0.f, 0.f, 0.f, 0.f};
      #pragma unroll
      for (int nt = 0; nt < 4; ++nt) {
        acc[nt] = __builtin_amdgcn_mfma_f32_16x16x32_bf16(a0, bfr[nt][0], acc[nt], 0, 0, 0);
        acc[nt] = __builtin_amdgcn_mfma_f32_16x16x32_bf16(a1, bfr[nt][1], acc[nt], 0, 0, 0);
      }
      float sq[4];
      #pragma unroll
      for (int r = 0; r < 4; ++r)
        sq[r] = acc[0][r] * acc[0][r] + acc[1][r] * acc[1][r] +
                acc[2][r] * acc[2][r] + acc[3][r] * acc[3][r];
      #pragma unroll
      for (int mk = 1; mk < 16; mk <<= 1) {
        #pragma unroll
        for (int r = 0; r < 4; ++r) sq[r] += __shfl_xor(sq[r], mk, 64);
      }
      #pragma unroll
      for (int r = 0; r < 4; ++r) {
        float s2 = cf * cf * sq[r];
        float g = cf * s2 / ((1.f + s2) * sqrtf(s2 + FEPS));
        size_t base = ((size_t)j * JB + (rb + quad * 4 + r)) * 64;
        #pragma unroll
        for (int nt = 0; nt < 4; ++nt)
          out[base + nt * 16 + m] = g * acc[nt][r];
      }
    }
  }
}

extern "C" void kernel_launch(void* const* d_in, const int* in_sizes, int n_in,
                              void* d_out, int out_size, void* d_ws, size_t ws_size,
                              hipStream_t stream) {
  const float* x = (const float*)d_in[0];   // (8,32,512,64) f32
  const float* w = (const float*)d_in[1];   // (8,8,64,64)  f32
  float* out = (float*)d_out;               // (8,32,512,64) f32
  float* ws = (float*)d_ws;

  k_main<<<1024, 256, 0, stream>>>(x, w, ws);
  k_t1  <<<512,  256, 0, stream>>>(w, ws);
  k_out <<<512,  256, 0, stream>>>(w, out, ws);
}

// Round 10
// 124.600 us; speedup vs baseline: 1.1411x; 1.1411x over previous
//
#include <hip/hip_runtime.h>
#include <math.h>

#define JB   16384
#define FEPS 1e-9f
#define PADX 72     // LDS row stride (ushorts): 144 B, 16B-aligned, <=2-way banks
#define INV_JB2 (1.0f / ((float)JB * (float)JB))

// ws float offsets — every region fully written before read; NO memset needed
#define WS_BD0   0        // 64 : Bd0[i*8+j]
#define WS_BD1   64       // 64 : Bd1[i*8+j]  (zeroed by k_bd0, atomicAdd by k_t1)
#define WS_M     128      // 4096 : M[i][j][e] = (W[i][j]^T um[i])[e]
#define WS_UMP   4224     // 512*64 : u_mean partials [i*64+chunk][d]
#define WS_Q0P   36992    // 64*8*64 : q0 partials [rc][j][e] (= W7^T t0_blk)
#define WS_R2V   69760    // 16384*8 : r2[rv][j]  (rv = s*32+b, output row order)
#define WS_X7BV  200832   // 524288 fl (1M ushorts): bf16 x7, rv-order [rv][d]
#define WS_BT    725120   // 16384 fl (32K ushorts): Bt[n][k], n = j*64+e

typedef short short8 __attribute__((ext_vector_type(8)));
typedef float f32x4  __attribute__((ext_vector_type(4)));

static __device__ inline ushort f2bf(float f) {
  union { float f; unsigned u; } a; a.f = f;
  unsigned u = a.u;
  u += 0x7fffu + ((u >> 16) & 1u);   // RNE
  return (ushort)(u >> 16);
}
static __device__ inline float bf2f(ushort h) {
  union { unsigned u; float f; } c; c.u = ((unsigned)h) << 16;
  return c.f;
}

// ---------------------------------------------------------------- k_main
// blocks 0..511  : um-scan of x; i==7 blocks also emit bf16 x7 (rv-order).
// blocks 512..1023: MFMA GEMM (rc, j): r2[rv][j] + q0_parts (W7^T-contracted
//                  t0 partials, c0 = 1/8); rc==0 blocks persist bt.
__global__ __launch_bounds__(256) void k_main(const float* __restrict__ x,
                                              const float* __restrict__ w,
                                              float* __restrict__ ws) {
  int blk = blockIdx.x, t = threadIdx.x;
  __shared__ float4 s4[256];          // scan path (4 KB)
  __shared__ float wl[4096];          // gemm path: w7j stage (16 KB)
  __shared__ ushort x7l[128 * PADX];  // gemm path: bf16 rows (18 KB)
  __shared__ float gs[128];
  __shared__ float red[256];
  __shared__ float tl0[64];
  ushort* x7bv = (ushort*)(ws + WS_X7BV);
  ushort* bt   = (ushort*)(ws + WS_BT);

  if (blk < 512) {                    // ---------- um-scan path
    int i = blk >> 6, c = blk & 63;
    int q = t & 15, rsub = t >> 4;
    const float4* xr = (const float4*)(x + ((size_t)i * JB + c * 256) * 64);
    float4 a = make_float4(0.f, 0.f, 0.f, 0.f);
    for (int rr = rsub; rr < 256; rr += 16) {
      float4 v = xr[rr * 16 + q];
      a.x += v.x; a.y += v.y; a.z += v.z; a.w += v.w;
      if (i == 7) {                   // uniform branch
        ushort4 h = make_ushort4(f2bf(v.x), f2bf(v.y), f2bf(v.z), f2bf(v.w));
        int rn = c * 256 + rr;
        int rv = ((rn & 511) << 5) | (rn >> 9);   // rv = s*32 + b
        *(ushort4*)(x7bv + (size_t)rv * 64 + q * 4) = h;
      }
    }
    s4[t] = a;
    __syncthreads();
    if (t < 16) {
      float4 s = s4[t];
      for (int k = 1; k < 16; ++k) {
        float4 v = s4[t + k * 16];
        s.x += v.x; s.y += v.y; s.z += v.z; s.w += v.w;
      }
      *(float4*)(ws + WS_UMP + (size_t)blk * 64 + t * 4) = s;
    }
    return;
  }

  // ---------- GEMM path
  int bid = blk - 512;
  int j = bid & 7, rc = bid >> 3, rm0 = rc * 256;
  int lane = t & 63, wv = t >> 6, m = lane & 15, quad = lane >> 4;

  const float* w7j = w + (size_t)(56 + j) * 4096;
  #pragma unroll
  for (int k = 0; k < 16; ++k) wl[t + k * 256] = w7j[t + k * 256];
  __syncthreads();

  short8 bfr[4][2];
  #pragma unroll
  for (int nt = 0; nt < 4; ++nt)
    #pragma unroll
    for (int kb = 0; kb < 2; ++kb) {
      short8 hv;
      #pragma unroll
      for (int u = 0; u < 8; ++u)
        hv[u] = (short)f2bf(wl[(kb * 32 + quad * 8 + u) * 64 + nt * 16 + m]);
      bfr[nt][kb] = hv;
    }
  if (rc == 0) {                      // persist bt for k_out
    #pragma unroll
    for (int nt = 0; nt < 4; ++nt)
      #pragma unroll
      for (int kb = 0; kb < 2; ++kb)
        *(short8*)(bt + ((size_t)j * 64 + nt * 16 + m) * 64 + kb * 32 + quad * 8) = bfr[nt][kb];
  }

  const float* x7 = x + (size_t)7 * JB * 64;
  float tacc = 0.f;
  #pragma unroll
  for (int h = 0; h < 2; ++h) {
    #pragma unroll
    for (int s = 0; s < 2; ++s) {
      int rb = rm0 + h * 128 + s * 64 + wv * 16;
      const float* ap = x7 + (size_t)(rb + m) * 64;
      float4 f0 = *(const float4*)(ap + quad * 8);
      float4 f1 = *(const float4*)(ap + quad * 8 + 4);
      float4 f2 = *(const float4*)(ap + 32 + quad * 8);
      float4 f3 = *(const float4*)(ap + 32 + quad * 8 + 4);
      short8 a0, a1;
      a0[0] = (short)f2bf(f0.x); a0[1] = (short)f2bf(f0.y);
      a0[2] = (short)f2bf(f0.z); a0[3] = (short)f2bf(f0.w);
      a0[4] = (short)f2bf(f1.x); a0[5] = (short)f2bf(f1.y);
      a0[6] = (short)f2bf(f1.z); a0[7] = (short)f2bf(f1.w);
      a1[0] = (short)f2bf(f2.x); a1[1] = (short)f2bf(f2.y);
      a1[2] = (short)f2bf(f2.z); a1[3] = (short)f2bf(f2.w);
      a1[4] = (short)f2bf(f3.x); a1[5] = (short)f2bf(f3.y);
      a1[6] = (short)f2bf(f3.z); a1[7] = (short)f2bf(f3.w);
      int lrow = s * 64 + wv * 16 + m;
      *(short8*)(x7l + lrow * PADX + quad * 8) = a0;        // stage for t0
      *(short8*)(x7l + lrow * PADX + 32 + quad * 8) = a1;

      f32x4 acc[4];
      #pragma unroll
      for (int nt = 0; nt < 4; ++nt) acc[nt] = (f32x4){0.f, 0.f, 0.f, 0.f};
      #pragma unroll
      for (int nt = 0; nt < 4; ++nt) {
        acc[nt] = __builtin_amdgcn_mfma_f32_16x16x32_bf16(a0, bfr[nt][0], acc[nt], 0, 0, 0);
        acc[nt] = __builtin_amdgcn_mfma_f32_16x16x32_bf16(a1, bfr[nt][1], acc[nt], 0, 0, 0);
      }
      float sq[4];
      #pragma unroll
      for (int r = 0; r < 4; ++r)
        sq[r] = acc[0][r] * acc[0][r] + acc[1][r] * acc[1][r] +
                acc[2][r] * acc[2][r] + acc[3][r] * acc[3][r];
      #pragma unroll
      for (int mk = 1; mk < 16; mk <<= 1) {
        #pragma unroll
        for (int r = 0; r < 4; ++r) sq[r] += __shfl_xor(sq[r], mk, 64);
      }
      if (m == 0) {
        #pragma unroll
        for (int r = 0; r < 4; ++r) {
          int rn = rb + quad * 4 + r;
          int rv = ((rn & 511) << 5) | (rn >> 9);
          ws[WS_R2V + (size_t)rv * 8 + j] = sq[r];          // rv-order store
          float s2 = 0.015625f * sq[r];                     // (1/8)^2 * r2
          gs[s * 64 + wv * 16 + quad * 4 + r] =
              0.125f * s2 / ((1.f + s2) * sqrtf(s2 + FEPS));
        }
      }
    }
    __syncthreads();
    {
      int d = lane;
      float a = 0.f;
      #pragma unroll 8
      for (int r = 0; r < 32; ++r) {
        int row = wv * 32 + r;
        a += gs[row] * bf2f(x7l[row * PADX + d]);
      }
      tacc += a;
    }
    __syncthreads();
  }
  red[t] = tacc;
  __syncthreads();
  if (t < 64) tl0[t] = red[t] + red[t + 64] + red[t + 128] + red[t + 192];
  __syncthreads();
  {  // q0_blk[e] = sum_d t0_blk[d] * W7[j][d][e]  (wl already holds w7j)
    int e = t & 63, grp = t >> 6;
    float p = 0.f;
    #pragma unroll
    for (int d = grp * 16; d < grp * 16 + 16; ++d)
      p += tl0[d] * wl[d * 64 + e];
    red[t] = p;
  }
  __syncthreads();
  if (t < 64)
    ws[WS_Q0P + (size_t)(rc * 8 + j) * 64 + t] =
        red[t] + red[t + 64] + red[t + 128] + red[t + 192];
}

// ---------------------------------------------------------------- k_bd0
// Block (i,j), 64 threads: um[i] (UMP reduce), q0[j] (Q0P reduce),
// M[i][j][e] = (W[i][j]^T um)[e] (stored for k_t1),
// Bd0[i][j] = M . q0 / JB^2 ; zero Bd1[i][j].
__global__ __launch_bounds__(64) void k_bd0(const float* __restrict__ w,
                                            float* __restrict__ ws) {
  int i = blockIdx.x >> 3, j = blockIdx.x & 7;
  int t = threadIdx.x;                 // 64
  __shared__ float um_l[64], q0_l[64];
  {
    float s = 0.f;
    #pragma unroll 8
    for (int c = 0; c < 64; ++c) s += ws[WS_UMP + (size_t)(i * 64 + c) * 64 + t];
    um_l[t] = s;
    float q = 0.f;
    #pragma unroll 8
    for (int rc = 0; rc < 64; ++rc) q += ws[WS_Q0P + (size_t)(rc * 8 + j) * 64 + t];
    q0_l[t] = q;
  }
  __syncthreads();
  const float* wij = w + (size_t)(i * 8 + j) * 4096;
  float mv = 0.f;
  for (int d = 0; d < 64; ++d) mv += um_l[d] * wij[d * 64 + t];
  ws[WS_M + (size_t)(i * 8 + j) * 64 + t] = mv;
  float p = mv * q0_l[t];
  #pragma unroll
  for (int mk = 1; mk < 64; mk <<= 1) p += __shfl_xor(p, mk, 64);
  if (t == 0) {
    ws[WS_BD0 + i * 8 + j] = p * INV_JB2;
    ws[WS_BD1 + i * 8 + j] = 0.f;
  }
}

// ---------------------------------------------------------------- k_t1
// c1[j] = softmax(Bd0)[7][j] (trivial inline). t1 partials from bf16 x7 +
// r2; block-local t1 contracted through W7^T -> q1; Bd1 += M . q1 / JB^2
// via 8 fp32 atomics (no TP1, no reducer dispatch).
__global__ __launch_bounds__(256) void k_t1(const float* __restrict__ w,
                                            float* __restrict__ ws) {
  int t = threadIdx.x, blk = blockIdx.x;
  int lane = t & 63, wv = t >> 6;
  int j = blk & 7, rc = blk >> 3, rm0 = rc * 256;
  __shared__ ushort x7l[128 * PADX];
  __shared__ float gs[128];
  __shared__ float red[256];
  __shared__ float tl0[64], qs[64];
  __shared__ float cl;
  ushort* x7bv = (ushort*)(ws + WS_X7BV);

  if (t == 0) {
    float bv[8], mx = -1e30f;
    for (int i = 0; i < 8; ++i) { bv[i] = ws[WS_BD0 + i * 8 + j]; mx = fmaxf(mx, bv[i]); }
    float ss = 0.f;
    for (int i = 0; i < 8; ++i) ss += expf(bv[i] - mx);
    cl = expf(bv[7] - mx) / ss;
  }
  __syncthreads();
  float c1 = cl;

  float tacc = 0.f;
  #pragma unroll
  for (int h = 0; h < 2; ++h) {
    int rbh = rm0 + h * 128;
    #pragma unroll
    for (int k = 0; k < 4; ++k) {
      int c16 = t + k * 256;
      int row = c16 >> 3, seg = c16 & 7;
      *(short8*)(x7l + row * PADX + seg * 8) =
          *(const short8*)(x7bv + (size_t)(rbh + row) * 64 + seg * 8);
    }
    if (t < 128) {
      float r2v = ws[WS_R2V + (size_t)(rbh + t) * 8 + j];
      float s2 = c1 * c1 * r2v;
      gs[t] = c1 * s2 / ((1.f + s2) * sqrtf(s2 + FEPS));
    }
    __syncthreads();
    {
      int d = lane;
      float a = 0.f;
      #pragma unroll 8
      for (int r = 0; r < 32; ++r) {
        int row = wv * 32 + r;
        a += gs[row] * bf2f(x7l[row * PADX + d]);
      }
      tacc += a;
    }
    __syncthreads();
  }
  red[t] = tacc;
  __syncthreads();
  if (t < 64) tl0[t] = red[t] + red[t + 64] + red[t + 128] + red[t + 192];
  __syncthreads();
  {  // q1[e] = sum_d t1_blk[d] * W7[j][d][e]  (w L2-hot)
    int e = t & 63, grp = t >> 6;
    const float* w7j = w + (size_t)(56 + j) * 4096;
    float p = 0.f;
    #pragma unroll
    for (int d = grp * 16; d < grp * 16 + 16; ++d)
      p += tl0[d] * w7j[d * 64 + e];
    red[t] = p;
  }
  __syncthreads();
  if (t < 64) qs[t] = red[t] + red[t + 64] + red[t + 128] + red[t + 192];
  __syncthreads();
  if (t < 8) {
    const float* Mi = ws + WS_M + (size_t)(t * 8 + j) * 64;
    float b = 0.f;
    for (int e = 0; e < 64; ++e) b += Mi[e] * qs[e];
    atomicAdd(&ws[WS_BD1 + t * 8 + j], b * INV_JB2);
  }
}

// ---------------------------------------------------------------- k_out
// cf[j] = softmax(Bd0+Bd1)[7][j] (trivial inline);
// out[j][rv][e] = g(cf, r2) * p   (rv-order rows/stores, MFMA GEMM)
__global__ __launch_bounds__(256) void k_out(float* __restrict__ out,
                                             float* __restrict__ ws) {
  int t = threadIdx.x, blk = blockIdx.x;
  int lane = t & 63, wv = t >> 6, m = lane & 15, quad = lane >> 4;
  int j = blk & 7, rc = blk >> 3, rm0 = rc * 256;
  __shared__ float cl;
  ushort* x7bv = (ushort*)(ws + WS_X7BV);
  ushort* bt   = (ushort*)(ws + WS_BT);
  if (t == 0) {
    float bv[8], mx = -1e30f;
    for (int i = 0; i < 8; ++i) {
      bv[i] = ws[WS_BD0 + i * 8 + j] + ws[WS_BD1 + i * 8 + j];
      mx = fmaxf(mx, bv[i]);
    }
    float ss = 0.f;
    for (int i = 0; i < 8; ++i) ss += expf(bv[i] - mx);
    cl = expf(bv[7] - mx) / ss;
  }
  __syncthreads();
  float cf = cl;

  short8 bfr[4][2];
  const ushort* btj = bt + (size_t)(j * 64) * 64;
  #pragma unroll
  for (int nt = 0; nt < 4; ++nt)
    #pragma unroll
    for (int kb = 0; kb < 2; ++kb)
      bfr[nt][kb] = *(const short8*)(btj + (size_t)(nt * 16 + m) * 64 + kb * 32 + quad * 8);

  #pragma unroll
  for (int h = 0; h < 2; ++h) {
    #pragma unroll
    for (int s = 0; s < 2; ++s) {
      int rb = rm0 + h * 128 + s * 64 + wv * 16;   // rv-order rows
      const ushort* ap = x7bv + (size_t)(rb + m) * 64 + quad * 8;
      short8 a0 = *(const short8*)ap;
      short8 a1 = *(const short8*)(ap + 32);
      f32x4 acc[4];
      #pragma unroll
      for (int nt = 0; nt < 4; ++nt) acc[nt] = (f32x4){0.f, 0.f, 0.f, 0.f};
      #pragma unroll
      for (int nt = 0; nt < 4; ++nt) {
        acc[nt] = __builtin_amdgcn_mfma_f32_16x16x32_bf16(a0, bfr[nt][0], acc[nt], 0, 0, 0);
        acc[nt] = __builtin_amdgcn_mfma_f32_16x16x32_bf16(a1, bfr[nt][1], acc[nt], 0, 0, 0);
      }
      float sq[4];
      #pragma unroll
      for (int r = 0; r < 4; ++r)
        sq[r] = acc[0][r] * acc[0][r] + acc[1][r] * acc[1][r] +
                acc[2][r] * acc[2][r] + acc[3][r] * acc[3][r];
      #pragma unroll
      for (int mk = 1; mk < 16; mk <<= 1) {
        #pragma unroll
        for (int r = 0; r < 4; ++r) sq[r] += __shfl_xor(sq[r], mk, 64);
      }
      #pragma unroll
      for (int r = 0; r < 4; ++r) {
        float s2 = cf * cf * sq[r];
        float g = cf * s2 / ((1.f + s2) * sqrtf(s2 + FEPS));
        size_t base = ((size_t)j * JB + (rb + quad * 4 + r)) * 64;
        #pragma unroll
        for (int nt = 0; nt < 4; ++nt)
          out[base + nt * 16 + m] = g * acc[nt][r];
      }
    }
  }
}

extern "C" void kernel_launch(void* const* d_in, const int* in_sizes, int n_in,
                              void* d_out, int out_size, void* d_ws, size_t ws_size,
                              hipStream_t stream) {
  const float* x = (const float*)d_in[0];   // (8,32,512,64) f32
  const float* w = (const float*)d_in[1];   // (8,8,64,64)  f32
  float* out = (float*)d_out;               // (8,32,512,64) f32
  float* ws = (float*)d_ws;

  k_main<<<1024, 256, 0, stream>>>(x, w, ws);
  k_bd0 <<<64,   64,  0, stream>>>(w, ws);
  k_t1  <<<512,  256, 0, stream>>>(w, ws);
  k_out <<<512,  256, 0, stream>>>(out, ws);
}